// Round 10
// baseline (913.017 us; speedup 1.0000x reference)
//
#include <hip/hip_runtime.h>

#define TT 2048
#define II 8
#define HH 24
#define THRESH 0.1f
#define LOG2E 1.4426950408889634f

typedef float v4f __attribute__((ext_vector_type(4)));

// rotate within 16-lane row by N, add (DPP row_ror, VALU-only)
#define ROR_ADD(a, N)                                                          \
    {                                                                          \
        int t_ = __builtin_amdgcn_update_dpp(0, __float_as_int(a),             \
                                             0x120 + (N), 0xF, 0xF, false);    \
        (a) += __int_as_float(t_);                                             \
    }

// TWO batch elements per wave (grid 1024): weights, x addressing, loop control
// amortized over 2 recurrences; 2 independent dep chains give intra-wave ILP.
//  lane l32=j<24 (both halves): unit j. lo half owns rows (i_j,f_j), hi half
//  rows (g_j,o_j) — shared by both batches (2 dots/row = 4 dots/lane).
//  lanes 24-31: x prefetch for batch0; lanes 56-63: x prefetch for batch1.
// All lanes compute c,h for BOTH batches after permlane32 gate distribution.
// LDS vbuf[2][32] = [x(8);h(24)] per batch. Single wave -> no barriers
// (per-wave DS pipe is in-order). Per-lane x loads keep lgkmcnt DS-only (R9).
__global__ __launch_bounds__(64)
__attribute__((amdgpu_waves_per_eu(1, 1)))
void lstm_anom_kernel(const float* __restrict__ x,
                      const float* __restrict__ W_ih,
                      const float* __restrict__ W_hh,
                      const float* __restrict__ b_ih,
                      const float* __restrict__ b_hh,
                      const float* __restrict__ W_out,
                      const float* __restrict__ b_out,
                      float* __restrict__ out)
{
    __shared__ __align__(16) float vbuf[64];   // [batch][x0..x7,h0..h23]

    const int  lane  = threadIdx.x;
    const int  b0    = blockIdx.x * 2;
    const int  b1    = b0 + 1;
    const int  l32   = lane & 31;
    const bool hi    = lane >= 32;
    const bool unitL = (l32 < HH);
    const int  jc    = unitL ? l32 : 0;        // clamped for junk lanes
    const bool xL    = (l32 >= 24);            // x-stage lanes (both halves)
    const int  xk    = l32 - 24;

    const float* xb0 = x + (size_t)b0 * (TT * II);
    const float* xb1 = x + (size_t)b1 * (TT * II);
    const float* xbs = hi ? xb1 : xb0;         // this lane's staging batch

    // ---- persistent weights: 2 full gate rows per lane, v4f packed ----
    const int rowA = (hi ? 2 * HH : 0) + jc;   // lo: i-gate, hi: g-gate
    const int rowB = rowA + HH;                // lo: f-gate, hi: o-gate
    v4f wA4[8], wB4[8];
    wA4[0] = *(const v4f*)(W_ih + rowA * II);
    wA4[1] = *(const v4f*)(W_ih + rowA * II + 4);
    wB4[0] = *(const v4f*)(W_ih + rowB * II);
    wB4[1] = *(const v4f*)(W_ih + rowB * II + 4);
    #pragma unroll
    for (int q = 0; q < 6; ++q) {              // W_hh rows, 16B-aligned steps
        wA4[2 + q] = *(const v4f*)(W_hh + rowA * HH + q * 4);
        wB4[2 + q] = *(const v4f*)(W_hh + rowB * HH + q * 4);
    }
    const float biasA = b_ih[rowA] + b_hh[rowA];
    const float biasB = b_ih[rowB] + b_hh[rowB];
    // nonlin A: lo -> sigmoid(a), hi -> tanh(a) = 2*sigmoid(2a)-1, uniform code
    const float kA = hi ? (-2.f * LOG2E) : (-LOG2E);
    const float mA = hi ? 2.f : 1.f;
    const float nA = hi ? -1.f : 0.f;
    const float woutj = unitL ? W_out[jc] : 0.f;
    const float bout  = b_out[0];

    // ---- init: vbuf[hi][l32] = [x row0; zeros]; x pipeline in xL lanes ----
    vbuf[hi * 32 + l32] = (l32 < 8) ? xbs[l32] : 0.f;
    float xA = 0.f, xB = 0.f;
    if (xL) xA = xbs[II + xk];                 // x[b][1][k], per-lane load

    const v4f* pv = (const v4f*)vbuf;
    v4f v0[8], v1[8];
    #pragma unroll
    for (int q = 0; q < 8; ++q) { v0[q] = pv[q]; v1[q] = pv[8 + q]; }

    float pred0 = v0[0].x, pred1 = v1[0].x;    // = x[b][0][0] -> no sub at t=0
    float cst0 = 0.f, cst1 = 0.f, ps0 = 0.f, ps1 = 0.f;

    for (int t = 0; t < TT; ++t) {
        // anomaly substitution on input 0 (wave-uniform, in registers)
        v0[0].x = (fabsf(pred0 - v0[0].x) > THRESH) ? pred0 : v0[0].x;
        v1[0].x = (fabsf(pred1 - v1[0].x) > THRESH) ? pred1 : v1[0].x;

        // ---- 4 dots/lane (2 rows x 2 batches), v4 packed FMA ----
        v4f aA0 = (v4f){biasA, 0.f, 0.f, 0.f};
        v4f aB0 = (v4f){biasB, 0.f, 0.f, 0.f};
        v4f aA1 = (v4f){biasA, 0.f, 0.f, 0.f};
        v4f aB1 = (v4f){biasB, 0.f, 0.f, 0.f};
        #pragma unroll
        for (int q = 0; q < 8; ++q) {
            aA0 = __builtin_elementwise_fma(wA4[q], v0[q], aA0);
            aB0 = __builtin_elementwise_fma(wB4[q], v0[q], aB0);
            aA1 = __builtin_elementwise_fma(wA4[q], v1[q], aA1);
            aB1 = __builtin_elementwise_fma(wB4[q], v1[q], aB1);
        }
        const float sA0v = (aA0.x + aA0.y) + (aA0.z + aA0.w);
        const float sB0v = (aB0.x + aB0.y) + (aB0.z + aB0.w);
        const float sA1v = (aA1.x + aA1.y) + (aA1.z + aA1.w);
        const float sB1v = (aB1.x + aB1.y) + (aB1.z + aB1.w);

        // ---- nonlinearities (once per gate per batch) ----
        const float sA0 = __builtin_amdgcn_rcpf(1.f + __builtin_amdgcn_exp2f(kA * sA0v));
        const float tA0 = fmaf(sA0, mA, nA);               // sig(i)/tanh(g) b0
        const float sB0 = __builtin_amdgcn_rcpf(1.f + __builtin_amdgcn_exp2f(-LOG2E * sB0v));
        const float sA1 = __builtin_amdgcn_rcpf(1.f + __builtin_amdgcn_exp2f(kA * sA1v));
        const float tA1 = fmaf(sA1, mA, nA);               // sig(i)/tanh(g) b1
        const float sB1 = __builtin_amdgcn_rcpf(1.f + __builtin_amdgcn_exp2f(-LOG2E * sB1v));

        // ---- distribute halves: every lane gets (ig,gg,fg,og) per batch ----
        auto rA0 = __builtin_amdgcn_permlane32_swap(__float_as_int(tA0), __float_as_int(tA0), false, false);
        auto rB0 = __builtin_amdgcn_permlane32_swap(__float_as_int(sB0), __float_as_int(sB0), false, false);
        auto rA1 = __builtin_amdgcn_permlane32_swap(__float_as_int(tA1), __float_as_int(tA1), false, false);
        auto rB1 = __builtin_amdgcn_permlane32_swap(__float_as_int(sB1), __float_as_int(sB1), false, false);
        const float ig0 = __int_as_float(rA0[0]), gg0 = __int_as_float(rA0[1]);
        const float fg0 = __int_as_float(rB0[0]), og0 = __int_as_float(rB0[1]);
        const float ig1 = __int_as_float(rA1[0]), gg1 = __int_as_float(rA1[1]);
        const float fg1 = __int_as_float(rB1[0]), og1 = __int_as_float(rB1[1]);

        cst0 = fmaf(fg0, cst0, ig0 * gg0);
        cst1 = fmaf(fg1, cst1, ig1 * gg1);
        const float sc0 = __builtin_amdgcn_rcpf(1.f + __builtin_amdgcn_exp2f(-2.f * LOG2E * cst0));
        const float sc1 = __builtin_amdgcn_rcpf(1.f + __builtin_amdgcn_exp2f(-2.f * LOG2E * cst1));
        const float h0 = og0 * fmaf(2.f, sc0, -1.f);
        const float h1 = og1 * fmaf(2.f, sc1, -1.f);

        // ---- stage next step: all 64 lanes write one distinct slot ----
        // lanes 0-23: h0 | 24-31: x0 | 32-55: h1 | 56-63: x1  (2-way bank
        // aliasing lane i vs i+32 only -> free per m136)
        vbuf[hi * 32 + (xL ? xk : 8 + l32)] = xL ? xA : (hi ? h1 : h0);
        if (xL) {                               // per-lane VECTOR load (vmcnt)
            int tn = t + 2; if (tn > TT - 1) tn = TT - 1;
            xB = xbs[(size_t)tn * II + xk];
        }

        // ---- heads: two independent permlane16+DPP reductions ----
        float p0 = woutj * h0, p1 = woutj * h1;
        {
            auto r0 = __builtin_amdgcn_permlane16_swap(__float_as_int(p0), __float_as_int(p0), false, false);
            auto r1 = __builtin_amdgcn_permlane16_swap(__float_as_int(p1), __float_as_int(p1), false, false);
            p0 = __int_as_float(r0[0]) + __int_as_float(r0[1]);
            p1 = __int_as_float(r1[0]) + __int_as_float(r1[1]);
        }
        ROR_ADD(p0, 8); ROR_ADD(p1, 8);
        ROR_ADD(p0, 4); ROR_ADD(p1, 4);
        ROR_ADD(p0, 2); ROR_ADD(p1, 2);
        ROR_ADD(p0, 1); ROR_ADD(p1, 1);
        pred0 = p0 + bout;
        pred1 = p1 + bout;

        // buffer preds; coalesced 256B flushes every 64 steps
        ps0 = ((t & 63) == lane) ? pred0 : ps0;
        ps1 = ((t & 63) == lane) ? pred1 : ps1;
        if ((t & 63) == 63) {
            out[(size_t)b0 * TT + (t - 63) + lane] = ps0;
            out[(size_t)b1 * TT + (t - 63) + lane] = ps1;
        }

        // ---- reload v for next step (broadcast ds_read_b128, DS-only) ----
        #pragma unroll
        for (int q = 0; q < 8; ++q) { v0[q] = pv[q]; v1[q] = pv[8 + q]; }
        if (xL) xA = xB;
    }
}

extern "C" void kernel_launch(void* const* d_in, const int* in_sizes, int n_in,
                              void* d_out, int out_size, void* d_ws, size_t ws_size,
                              hipStream_t stream) {
    const float* x     = (const float*)d_in[0];
    const float* W_ih  = (const float*)d_in[1];
    const float* W_hh  = (const float*)d_in[2];
    const float* b_ih  = (const float*)d_in[3];
    const float* b_hh  = (const float*)d_in[4];
    const float* W_out = (const float*)d_in[5];
    const float* b_out = (const float*)d_in[6];
    float* out = (float*)d_out;

    dim3 grid(1024);   // one wave per TWO batch elements
    dim3 block(64);
    lstm_anom_kernel<<<grid, block, 0, stream>>>(x, W_ih, W_hh, b_ih, b_hh,
                                                 W_out, b_out, out);
}

// Round 11
// 777.551 us; speedup vs baseline: 1.1742x; 1.1742x over previous
//
#include <hip/hip_runtime.h>

#define TT 2048
#define II 8
#define HH 24
#define THRESH 0.1f
#define LOG2E 1.4426950408889634f

typedef float v4f __attribute__((ext_vector_type(4)));

// rotate within 16-lane row by N, add (DPP row_ror, VALU-only)
#define ROR_ADD(a, N)                                                          \
    {                                                                          \
        int t_ = __builtin_amdgcn_update_dpp(0, __float_as_int(a),             \
                                             0x120 + (N), 0xF, 0xF, false);    \
        (a) += __int_as_float(t_);                                             \
    }

// One wave (= one block) per batch element; 2048 waves = 2 waves/SIMD.
//  lane l32=j<24, lo half : owns gate rows (i_j, f_j) — 2 full 32-wide dots
//  lane l32=j<24, hi half : owns gate rows (g_j, o_j)
//  lanes 24-31 (lo half)  : x-prefetch lanes (k=0..7), junk weights (clamped)
//  lanes 56-63            : junk (clamped row-0 weights), woutj=0 masks them
//
// R11 = R9 structure + v4f math everywhere (proven trajectory-safe in R10):
// weights and v load directly as 16B vectors -> zero repack v_movs in the
// loop. Per-lane x vector loads keep lgkmcnt DS-only (R9 finding: wave-
// uniform x loads become s_load -> every ds_read wait drains the prefetch).
// Single wave -> no __syncthreads (per-wave DS pipe is in-order).
__global__ __launch_bounds__(64)
__attribute__((amdgpu_waves_per_eu(2, 2)))
void lstm_anom_kernel(const float* __restrict__ x,
                      const float* __restrict__ W_ih,
                      const float* __restrict__ W_hh,
                      const float* __restrict__ b_ih,
                      const float* __restrict__ b_hh,
                      const float* __restrict__ W_out,
                      const float* __restrict__ b_out,
                      float* __restrict__ out)
{
    __shared__ __align__(16) float vbuf[32];   // [x0..x7; h0..h23]

    const int  lane  = threadIdx.x;
    const int  b     = blockIdx.x;
    const int  l32   = lane & 31;
    const bool hi    = lane >= 32;
    const bool unitL = (l32 < HH);
    const int  jc    = unitL ? l32 : 0;        // clamped for junk lanes
    const bool xL    = (!hi) && (l32 >= 24);   // lanes 24..31
    const int  xk    = l32 - 24;

    const float* xb = x + (size_t)b * (TT * II);

    // ---- persistent weights: 2 full gate rows per lane, v4f packed ----
    const int rowA = (hi ? 2 * HH : 0) + jc;   // lo: i-gate, hi: g-gate
    const int rowB = rowA + HH;                // lo: f-gate, hi: o-gate
    v4f wA4[8], wB4[8];
    wA4[0] = *(const v4f*)(W_ih + rowA * II);
    wA4[1] = *(const v4f*)(W_ih + rowA * II + 4);
    wB4[0] = *(const v4f*)(W_ih + rowB * II);
    wB4[1] = *(const v4f*)(W_ih + rowB * II + 4);
    #pragma unroll
    for (int q = 0; q < 6; ++q) {              // W_hh rows (24 floats, 16B ok)
        wA4[2 + q] = *(const v4f*)(W_hh + rowA * HH + q * 4);
        wB4[2 + q] = *(const v4f*)(W_hh + rowB * HH + q * 4);
    }
    const float biasA = b_ih[rowA] + b_hh[rowA];
    const float biasB = b_ih[rowB] + b_hh[rowB];
    // nonlin A: lo -> sigmoid(a), hi -> tanh(a) = 2*sigmoid(2a)-1, uniform code
    const float kA = hi ? (-2.f * LOG2E) : (-LOG2E);
    const float mA = hi ? 2.f : 1.f;
    const float nA = hi ? -1.f : 0.f;
    const float woutj = unitL ? W_out[jc] : 0.f;
    const float bout  = b_out[0];

    // ---- init: vbuf = [x[b][0][:8]; h0 = 0]; x pipeline in xL lanes ----
    if (lane < 32) vbuf[lane] = (lane < 8) ? xb[lane] : 0.f;
    float xA = 0.f, xB = 0.f;
    if (xL) xA = xb[II + xk];                  // x[b][1][k], per-lane load
    __syncthreads();                           // once, before the loop

    const v4f* pv = (const v4f*)vbuf;
    v4f vv[8];
    #pragma unroll
    for (int q = 0; q < 8; ++q) vv[q] = pv[q];

    float pred = vv[0].x;       // pred0 = x[b][0][0] -> no substitution at t=0
    float cst = 0.f, predsave = 0.f;

    for (int t = 0; t < TT; ++t) {
        // anomaly substitution on input 0 (wave-uniform, in registers)
        vv[0].x = (fabsf(pred - vv[0].x) > THRESH) ? pred : vv[0].x;

        // ---- 2 full 32-wide gate dots per lane, v4f packed FMA ----
        v4f accA = (v4f){biasA, 0.f, 0.f, 0.f};
        v4f accB = (v4f){biasB, 0.f, 0.f, 0.f};
        #pragma unroll
        for (int q = 0; q < 8; ++q) {
            accA = __builtin_elementwise_fma(wA4[q], vv[q], accA);
            accB = __builtin_elementwise_fma(wB4[q], vv[q], accB);
        }
        const float aA = (accA.x + accA.y) + (accA.z + accA.w);
        const float aB = (accB.x + accB.y) + (accB.z + accB.w);

        // ---- nonlinearities, once per gate ----
        const float sA = __builtin_amdgcn_rcpf(1.f + __builtin_amdgcn_exp2f(kA * aA));
        const float tA = fmaf(sA, mA, nA);                  // lo: sig(i), hi: tanh(g)
        const float sB = __builtin_amdgcn_rcpf(1.f + __builtin_amdgcn_exp2f(-LOG2E * aB));
                                                            // lo: sig(f), hi: sig(o)
        // ---- distribute halves: every lane gets (ig,gg,fg,og) ----
        auto rA = __builtin_amdgcn_permlane32_swap(__float_as_int(tA), __float_as_int(tA), false, false);
        auto rB = __builtin_amdgcn_permlane32_swap(__float_as_int(sB), __float_as_int(sB), false, false);
        const float ig = __int_as_float(rA[0]);
        const float gg = __int_as_float(rA[1]);
        const float fg = __int_as_float(rB[0]);
        const float og = __int_as_float(rB[1]);

        cst = fmaf(fg, cst, ig * gg);
        const float sc = __builtin_amdgcn_rcpf(1.f + __builtin_amdgcn_exp2f(-2.f * LOG2E * cst));
        const float tc = fmaf(2.f, sc, -1.f);               // tanh(c)
        const float h  = og * tc;

        // ---- stage next step's inputs: lanes 0-23 write h, 24-31 write x ----
        // banks 0..31 distinct, conflict-free; same-wave DS pipe is in-order
        if (lane < 32) vbuf[xL ? xk : (8 + l32)] = xL ? xA : h;
        if (xL) {                                // per-lane VECTOR load (vmcnt)
            int tn = t + 2; if (tn > TT - 1) tn = TT - 1;
            xB = xb[(size_t)tn * II + xk];
        }

        // ---- head: Σ_j wout_j*h_j (permlane16 fold + 4 DPP ror-adds) ----
        float p = woutj * h;
        {
            auto r = __builtin_amdgcn_permlane16_swap(__float_as_int(p), __float_as_int(p), false, false);
            p = __int_as_float(r[0]) + __int_as_float(r[1]);
        }
        ROR_ADD(p, 8); ROR_ADD(p, 4); ROR_ADD(p, 2); ROR_ADD(p, 1);
        pred = p + bout;

        // buffer pred; coalesced 256B flush every 64 steps
        predsave = ((t & 63) == lane) ? pred : predsave;
        if ((t & 63) == 63) out[(size_t)b * TT + (t - 63) + lane] = predsave;

        // ---- reload v for next step (broadcast ds_read_b128 -> v4f, direct)
        #pragma unroll
        for (int q = 0; q < 8; ++q) vv[q] = pv[q];
        if (xL) xA = xB;
    }
}

extern "C" void kernel_launch(void* const* d_in, const int* in_sizes, int n_in,
                              void* d_out, int out_size, void* d_ws, size_t ws_size,
                              hipStream_t stream) {
    const float* x     = (const float*)d_in[0];
    const float* W_ih  = (const float*)d_in[1];
    const float* W_hh  = (const float*)d_in[2];
    const float* b_ih  = (const float*)d_in[3];
    const float* b_hh  = (const float*)d_in[4];
    const float* W_out = (const float*)d_in[5];
    const float* b_out = (const float*)d_in[6];
    float* out = (float*)d_out;

    dim3 grid(2048);   // one wave per batch element
    dim3 block(64);
    lstm_anom_kernel<<<grid, block, 0, stream>>>(x, W_ih, W_hh, b_ih, b_hh,
                                                 W_out, b_out, out);
}

// Round 12
// 749.371 us; speedup vs baseline: 1.2184x; 1.0376x over previous
//
#include <hip/hip_runtime.h>

#define TT 2048
#define II 8
#define HH 24
#define THRESH 0.1f
#define LOG2E 1.4426950408889634f

typedef float v2f __attribute__((ext_vector_type(2)));

// rotate within 16-lane row by N, add (DPP row_ror, VALU-only)
#define ROR_ADD(a, N)                                                          \
    {                                                                          \
        int t_ = __builtin_amdgcn_update_dpp(0, __float_as_int(a),             \
                                             0x120 + (N), 0xF, 0xF, false);    \
        (a) += __int_as_float(t_);                                             \
    }

// One wave (= one block) per batch element; 2048 waves = 2 waves/SIMD.
//  lane l32=j<24, lo half : owns gate rows (i_j, f_j) — 2 full 32-wide pk-dots
//  lane l32=j<24, hi half : owns gate rows (g_j, o_j)
//  lanes 24-31 (lo half)  : x-prefetch lanes (k=0..7), junk weights (clamped)
//  lanes 56-63            : junk (clamped row-0 weights), woutj=0 masks them
//
// R12 = R9 + VOLATILE weight loads. R6/R7 lesson: plain loads are
// rematerializable, so asm keep-alives were satisfied by re-loading inside
// the loop every iteration (~150 issue-cy/step tax, VGPR stuck at 88).
// Volatile loads cannot be duplicated/sunk -> their results must be carried
// loop-resident in VGPRs (budget 256 at waves_per_eu(2,2)).
// Per-lane x vector loads keep lgkmcnt DS-only (R9). No barriers (1 wave).
__global__ __launch_bounds__(64)
__attribute__((amdgpu_waves_per_eu(2, 2)))
void lstm_anom_kernel(const float* __restrict__ x,
                      const float* __restrict__ W_ih,
                      const float* __restrict__ W_hh,
                      const float* __restrict__ b_ih,
                      const float* __restrict__ b_hh,
                      const float* __restrict__ W_out,
                      const float* __restrict__ b_out,
                      float* __restrict__ out)
{
    __shared__ __align__(16) float vbuf[32];   // [x0..x7; h0..h23]

    const int  lane  = threadIdx.x;
    const int  b     = blockIdx.x;
    const int  l32   = lane & 31;
    const bool hi    = lane >= 32;
    const bool unitL = (l32 < HH);
    const int  jc    = unitL ? l32 : 0;        // clamped for junk lanes
    const bool xL    = (!hi) && (l32 >= 24);   // lanes 24..31
    const int  xk    = l32 - 24;

    const float* xb = x + (size_t)b * (TT * II);

    // ---- persistent weights: 2 full gate rows per lane, packed f32x2 ----
    // Loaded VOLATILE so the values are non-rematerializable -> loop-resident.
    const int rowA = (hi ? 2 * HH : 0) + jc;   // lo: i-gate, hi: g-gate
    const int rowB = rowA + HH;                // lo: f-gate, hi: o-gate
    volatile const float* vW_ih = W_ih;
    volatile const float* vW_hh = W_hh;

    v2f wA2[16], wB2[16];
    #pragma unroll
    for (int k = 0; k < 4; ++k) {              // W_ih rows: 8 floats each
        wA2[k] = (v2f){ vW_ih[rowA * II + 2 * k], vW_ih[rowA * II + 2 * k + 1] };
        wB2[k] = (v2f){ vW_ih[rowB * II + 2 * k], vW_ih[rowB * II + 2 * k + 1] };
    }
    #pragma unroll
    for (int k = 0; k < 12; ++k) {             // W_hh rows: 24 floats each
        wA2[4 + k] = (v2f){ vW_hh[rowA * HH + 2 * k], vW_hh[rowA * HH + 2 * k + 1] };
        wB2[4 + k] = (v2f){ vW_hh[rowB * HH + 2 * k], vW_hh[rowB * HH + 2 * k + 1] };
    }
    const float biasA = b_ih[rowA] + b_hh[rowA];
    const float biasB = b_ih[rowB] + b_hh[rowB];
    // nonlin A: lo -> sigmoid(a), hi -> tanh(a) = 2*sigmoid(2a)-1, uniform code
    const float kA = hi ? (-2.f * LOG2E) : (-LOG2E);
    const float mA = hi ? 2.f : 1.f;
    const float nA = hi ? -1.f : 0.f;
    const float woutj = unitL ? W_out[jc] : 0.f;
    const float bout  = b_out[0];

    // ---- init: vbuf = [x[b][0][:8]; h0 = 0]; x pipeline in xL lanes ----
    if (lane < 32) vbuf[lane] = (lane < 8) ? xb[lane] : 0.f;
    float xA = 0.f, xB = 0.f;
    if (xL) xA = xb[II + xk];                  // x[b][1][k], per-lane load
    __syncthreads();                           // once, before the loop

    v2f v2r[16];
    #pragma unroll
    for (int c8 = 0; c8 < 8; ++c8) {
        const float4 q = *(const float4*)&vbuf[c8 * 4];
        v2r[c8 * 2]     = (v2f){q.x, q.y};
        v2r[c8 * 2 + 1] = (v2f){q.z, q.w};
    }
    float pred = v2r[0].x;      // pred0 = x[b][0][0] -> no substitution at t=0
    float cst = 0.f, predsave = 0.f;

    for (int t = 0; t < TT; ++t) {
        // anomaly substitution on input 0 (wave-uniform, in registers)
        v2r[0].x = (fabsf(pred - v2r[0].x) > THRESH) ? pred : v2r[0].x;

        // ---- 2 full 32-wide gate dots per lane, packed FMA ----
        v2f accA = (v2f){biasA, 0.f};
        v2f accB = (v2f){biasB, 0.f};
        #pragma unroll
        for (int k = 0; k < 16; ++k) {
            accA = __builtin_elementwise_fma(wA2[k], v2r[k], accA);
            accB = __builtin_elementwise_fma(wB2[k], v2r[k], accB);
        }
        const float aA = accA.x + accA.y;
        const float aB = accB.x + accB.y;

        // ---- nonlinearities, once per gate ----
        const float sA = __builtin_amdgcn_rcpf(1.f + __builtin_amdgcn_exp2f(kA * aA));
        const float tA = fmaf(sA, mA, nA);                  // lo: sig(i), hi: tanh(g)
        const float sB = __builtin_amdgcn_rcpf(1.f + __builtin_amdgcn_exp2f(-LOG2E * aB));
                                                            // lo: sig(f), hi: sig(o)
        // ---- distribute halves: every lane gets (ig,gg,fg,og) ----
        auto rA = __builtin_amdgcn_permlane32_swap(__float_as_int(tA), __float_as_int(tA), false, false);
        auto rB = __builtin_amdgcn_permlane32_swap(__float_as_int(sB), __float_as_int(sB), false, false);
        const float ig = __int_as_float(rA[0]);
        const float gg = __int_as_float(rA[1]);
        const float fg = __int_as_float(rB[0]);
        const float og = __int_as_float(rB[1]);

        cst = fmaf(fg, cst, ig * gg);
        const float sc = __builtin_amdgcn_rcpf(1.f + __builtin_amdgcn_exp2f(-2.f * LOG2E * cst));
        const float tc = fmaf(2.f, sc, -1.f);               // tanh(c)
        const float h  = og * tc;

        // ---- stage next step's inputs: lanes 0-23 write h, 24-31 write x ----
        // banks 0..31 distinct, conflict-free; same-wave DS pipe is in-order
        if (lane < 32) vbuf[xL ? xk : (8 + l32)] = xL ? xA : h;
        if (xL) {                                // per-lane VECTOR load (vmcnt)
            int tn = t + 2; if (tn > TT - 1) tn = TT - 1;
            xB = xb[(size_t)tn * II + xk];
        }

        // ---- head: Σ_j wout_j*h_j (permlane16 fold + 4 DPP ror-adds) ----
        float p = woutj * h;
        {
            auto r = __builtin_amdgcn_permlane16_swap(__float_as_int(p), __float_as_int(p), false, false);
            p = __int_as_float(r[0]) + __int_as_float(r[1]);
        }
        ROR_ADD(p, 8); ROR_ADD(p, 4); ROR_ADD(p, 2); ROR_ADD(p, 1);
        pred = p + bout;

        // buffer pred; coalesced 256B flush every 64 steps
        predsave = ((t & 63) == lane) ? pred : predsave;
        if ((t & 63) == 63) out[(size_t)b * TT + (t - 63) + lane] = predsave;

        // ---- reload v for next step (broadcast ds_read_b128, DS-only) ----
        #pragma unroll
        for (int c8 = 0; c8 < 8; ++c8) {
            const float4 q = *(const float4*)&vbuf[c8 * 4];
            v2r[c8 * 2]     = (v2f){q.x, q.y};
            v2r[c8 * 2 + 1] = (v2f){q.z, q.w};
        }
        if (xL) xA = xB;
    }
}

extern "C" void kernel_launch(void* const* d_in, const int* in_sizes, int n_in,
                              void* d_out, int out_size, void* d_ws, size_t ws_size,
                              hipStream_t stream) {
    const float* x     = (const float*)d_in[0];
    const float* W_ih  = (const float*)d_in[1];
    const float* W_hh  = (const float*)d_in[2];
    const float* b_ih  = (const float*)d_in[3];
    const float* b_hh  = (const float*)d_in[4];
    const float* W_out = (const float*)d_in[5];
    const float* b_out = (const float*)d_in[6];
    float* out = (float*)d_out;

    dim3 grid(2048);   // one wave per batch element
    dim3 block(64);
    lstm_anom_kernel<<<grid, block, 0, stream>>>(x, W_ih, W_hh, b_ih, b_hh,
                                                 W_out, b_out, out);
}